// Round 1
// 161.942 us; speedup vs baseline: 1.0277x; 1.0277x over previous
//
#include <hip/hip_runtime.h>
#include <hip/hip_bf16.h>

typedef __attribute__((ext_vector_type(8))) short short8;
typedef __attribute__((ext_vector_type(4))) float f32x4;

#define S_LEN 2048
#define NH 16
#define NKV 8
#define HD 64
#define WIN 512
#define DMODEL 1024
#define LOG2_10000 13.287712379549449f

// async 16B global -> LDS (wave-uniform LDS base + lane*16 semantics)
#define GLOAD16(g, l)                                                        \
    __builtin_amdgcn_global_load_lds(                                        \
        (const __attribute__((address_space(1))) unsigned int*)(g),          \
        (__attribute__((address_space(3))) unsigned int*)(l), 16, 0, 0)

// ---------------- cast X (fp32 -> bf16), vectorized ----------------
__global__ void cast_bf16_kernel(const float* __restrict__ X,
                                 __hip_bfloat16* __restrict__ Y, int n) {
    int i = (blockIdx.x * 256 + threadIdx.x) * 4;
    if (i + 3 < n) {
        float4 v = *reinterpret_cast<const float4*>(X + i);
        Y[i + 0] = __float2bfloat16(v.x);
        Y[i + 1] = __float2bfloat16(v.y);
        Y[i + 2] = __float2bfloat16(v.z);
        Y[i + 3] = __float2bfloat16(v.w);
    }
}

// ------- fused transpose+cast of all 4 weights (z selects matrix) -------
__global__ void transpose_cast4_kernel(const float* __restrict__ W0,
                                       const float* __restrict__ W1,
                                       const float* __restrict__ W2,
                                       const float* __restrict__ W3,
                                       __hip_bfloat16* __restrict__ WqkvT,
                                       __hip_bfloat16* __restrict__ WoT) {
    __shared__ float tile[32][33];
    const int K = DMODEL;
    const float* W;
    __hip_bfloat16* WT;
    int N;
    switch (blockIdx.z) {
        case 0: W = W0; WT = WqkvT;                          N = 1024; break;
        case 1: W = W1; WT = WqkvT + (size_t)1024 * K;       N = 512;  break;
        case 2: W = W2; WT = WqkvT + (size_t)1536 * K;       N = 512;  break;
        default: W = W3; WT = WoT;                           N = 1024; break;
    }
    if ((int)blockIdx.x * 32 >= N) return;
    int nx = blockIdx.x * 32 + threadIdx.x;
    int k0 = blockIdx.y * 32;
#pragma unroll
    for (int r = 0; r < 4; ++r) {
        int k = k0 + threadIdx.y + r * 8;
        tile[threadIdx.y + r * 8][threadIdx.x] = W[(size_t)k * N + nx];
    }
    __syncthreads();
#pragma unroll
    for (int r = 0; r < 4; ++r) {
        int nn = blockIdx.x * 32 + threadIdx.y + r * 8;
        int kk = k0 + threadIdx.x;
        WT[(size_t)nn * K + kk] = __float2bfloat16(tile[threadIdx.x][threadIdx.y + r * 8]);
    }
}

// ------------- GEMM: 128(M)x64(N) tile, 128 thr = 2 waves, DMA dbuf -----------
// ROUND 13: r12's 128x128/256-thr tile gave QKV only 512 blocks (2/CU) and
// out-proj 256 (1/CU) — grid-starved (m102: 320 TF at grid~256 vs 833 at
// ~1024). Halved tile N: wave-tile stays 64x64 (wave w = rows 64w, all 64
// cols). QKV grid 1024 (4/CU), out-proj 512 (2/CU); LDS 24 KB/block.
// MODE 0: fused QKV epilogue, in-register RoPE on Q/K (__cosf/__sinf ONLY —
//         libm calls spill the acc array). MODE 1: fp32 C.
template <int MODE>
__global__ __launch_bounds__(128) void gemm128_kernel(
    const __hip_bfloat16* __restrict__ A,
    const __hip_bfloat16* __restrict__ BT,
    void* __restrict__ o0, void* __restrict__ o1, void* __restrict__ o2,
    int N, int K) {
    __shared__ __hip_bfloat16 ldsA[2][128 * 32];   // 16 KB
    __shared__ __hip_bfloat16 ldsB[2][64 * 32];    // 8 KB
    const int tx = threadIdx.x;
    const int wave = tx >> 6;
    const int lane = tx & 63;
    const int l16 = lane & 15;
    const int quad = lane >> 4;
    const int col0 = blockIdx.x * 64;
    const int row0 = blockIdx.y * 128;
    const int wrow = wave * 64;

    f32x4 acc[4][4] = {};

    const int arow = tx >> 2;            // 0..31
    const int kc8 = (tx & 3) * 8;
    const __hip_bfloat16* gA = A + (size_t)(row0 + arow) * K + kc8;
    const __hip_bfloat16* gB = BT + (size_t)(col0 + arow) * K + kc8;

    auto stage = [&](int k0, int bf) {
        char* lA = (char*)(&ldsA[bf][0]) + tx * 16;
        char* lB = (char*)(&ldsB[bf][0]) + tx * 16;
#pragma unroll
        for (int r = 0; r < 4; ++r)
            GLOAD16(gA + (size_t)(r * 32) * K + k0, lA + r * 2048);
#pragma unroll
        for (int r = 0; r < 2; ++r)
            GLOAD16(gB + (size_t)(r * 32) * K + k0, lB + r * 2048);
    };

    stage(0, 0);
    int buf = 0;
    for (int k0 = 0; k0 < K; k0 += 32) {
        __syncthreads();                            // drains DMA into [buf]
        if (k0 + 32 < K) stage(k0 + 32, buf ^ 1);   // lands by next barrier
        short8 af[4], bf4[4];
#pragma unroll
        for (int i = 0; i < 4; ++i) {
            af[i] = *reinterpret_cast<const short8*>(
                &ldsA[buf][0] + (wrow + i * 16 + l16) * 32 + quad * 8);
            bf4[i] = *reinterpret_cast<const short8*>(
                &ldsB[buf][0] + (i * 16 + l16) * 32 + quad * 8);
        }
#pragma unroll
        for (int mi = 0; mi < 4; ++mi)
#pragma unroll
            for (int ni = 0; ni < 4; ++ni)
                acc[mi][ni] = __builtin_amdgcn_mfma_f32_16x16x32_bf16(
                    af[mi], bf4[ni], acc[mi][ni], 0, 0, 0);
        buf ^= 1;
    }

    const int rbase = row0 + wrow;
    if (MODE == 0) {
        const int cbaseg = col0;                    // 64-aligned global col
        const bool isQ = (cbaseg < DMODEL);
        const bool isK = (cbaseg >= DMODEL) && (cbaseg < DMODEL + 512);
        if (isQ || isK) {
            float invf[2];
            invf[0] = exp2f(-(float)(l16)      * (LOG2_10000 / 32.0f));
            invf[1] = exp2f(-(float)(16 + l16) * (LOG2_10000 / 32.0f));
#pragma unroll
            for (int mi = 0; mi < 4; ++mi)
#pragma unroll
                for (int r = 0; r < 4; ++r) {
                    int srow = (rbase + mi * 16 + quad * 4 + r) & (S_LEN - 1);
#pragma unroll
                    for (int ni = 0; ni < 2; ++ni) {
                        float ang = (float)srow * invf[ni];
                        float c = __cosf(ang), s = __sinf(ang);
                        float x1 = acc[mi][ni][r], x2 = acc[mi][ni + 2][r];
                        acc[mi][ni][r]     = x1 * c - x2 * s;
                        acc[mi][ni + 2][r] = x2 * c + x1 * s;
                    }
                }
            __hip_bfloat16* Co = (__hip_bfloat16*)(isQ ? o0 : o1);
            int cbase = isQ ? cbaseg : cbaseg - DMODEL;
            int rowstride = isQ ? (NH * HD) : (NKV * HD);
#pragma unroll
            for (int mi = 0; mi < 4; ++mi)
#pragma unroll
                for (int ni = 0; ni < 4; ++ni) {
                    size_t col = cbase + ni * 16 + l16;
#pragma unroll
                    for (int r = 0; r < 4; ++r)
                        Co[(size_t)(rbase + mi * 16 + quad * 4 + r) * rowstride + col] =
                            __float2bfloat16(acc[mi][ni][r]);
                }
        } else {                                   // V region -> transposed VT
            __hip_bfloat16* VTo = (__hip_bfloat16*)o2;
            int bb = row0 >> 11;
#pragma unroll
            for (int mi = 0; mi < 4; ++mi) {
                int s = ((rbase + mi * 16 + quad * 4) & (S_LEN - 1));
#pragma unroll
                for (int ni = 0; ni < 4; ++ni) {
                    int colv = cbaseg - 1536 + ni * 16 + l16;   // 0..511
                    int vh = colv >> 6, d = colv & 63;
                    alignas(8) __hip_bfloat16 hv[4];
#pragma unroll
                    for (int r = 0; r < 4; ++r) hv[r] = __float2bfloat16(acc[mi][ni][r]);
                    *reinterpret_cast<ushort4*>(
                        VTo + ((size_t)(bb * NKV + vh) * HD + d) * S_LEN + s) =
                        *reinterpret_cast<ushort4*>(hv);
                }
            }
        }
    } else {                                       // fp32 C
        float* Co = (float*)o0;
#pragma unroll
        for (int mi = 0; mi < 4; ++mi)
#pragma unroll
            for (int ni = 0; ni < 4; ++ni) {
                size_t col = col0 + ni * 16 + l16;
#pragma unroll
                for (int r = 0; r < 4; ++r)
                    Co[(size_t)(rbase + mi * 16 + quad * 4 + r) * N + col] = acc[mi][ni][r];
            }
    }
}

// ---------------- MFMA flash attention: head-split, DMA dbuf, swizzled ----
// ROUND 14: r13's GQA head-paired version ran grid 512 = 2 blocks/CU =
// 2 waves/SIMD — latency-bound (barriers + serial softmax chains with
// nothing to co-schedule). Split to 1 head/block: grid (32,16,2)=1024,
// LDS 52.5->40.0 KB (ldsP head dim + pad replaced by row-XOR unit swizzle)
// -> 4 blocks/CU, 16 waves/CU. K/V staged per head-block (2x L2 traffic,
// ~141 MB total, L2-resident -> ~4 us, negligible). Same MFMA/VALU totals.
__global__ __launch_bounds__(256, 4) void attn_mfma_kernel(
    const __hip_bfloat16* __restrict__ Q,
    const __hip_bfloat16* __restrict__ K,
    const __hip_bfloat16* __restrict__ VT,
    __hip_bfloat16* __restrict__ O) {
    __shared__ __hip_bfloat16 ldsK[2][64][64];       // 16 KB
    __shared__ __hip_bfloat16 ldsVT[2][64][64];      // 16 KB
    __shared__ __hip_bfloat16 ldsP[4][16][64];       // 8 KB, XOR unit swizzle
    const int tx = threadIdx.x;
    const int wave = tx >> 6;
    const int lane = tx & 63;
    const int l16 = lane & 15;
    const int quad = lane >> 4;
    const int q0 = blockIdx.x * 64;
    const int h = blockIdx.y;
    const int kvh = h >> 1;
    const int b = blockIdx.z;
    const int qi = q0 + wave * 16 + l16;

    short8 aq[2];
    {
        const __hip_bfloat16* qp =
            Q + (size_t)(b * S_LEN + qi) * (NH * HD) + h * HD + quad * 8;
        aq[0] = *reinterpret_cast<const short8*>(qp);
        aq[1] = *reinterpret_cast<const short8*>(qp + 32);
    }
    f32x4 acc_o[4] = {};
    float m = -1e30f, l = 0.f;
    const float SL2 = 0.125f * 1.4426950408889634f;   // scale * log2(e)

    // staging: row = tx>>3 (+32), chunk-in-row = tx&7, XOR source swizzle
    const int s_row = tx >> 3;
    const int s_c8 = (((tx & 7) ^ (s_row & 7))) * 8;
    const int sw = (l16 & 7);                          // reader swizzle key
    auto stage = [&](int j0, int bf) {
        char* lk = (char*)(&ldsK[bf][0][0]) + tx * 16;
        char* lv = (char*)(&ldsVT[bf][0][0]) + tx * 16;
#pragma unroll
        for (int r = 0; r < 2; ++r) {
            int row = s_row + r * 32;
            GLOAD16(K + (size_t)(b * S_LEN + j0 + row) * (NKV * HD) + kvh * HD + s_c8,
                    lk + r * 4096);
            GLOAD16(VT + ((size_t)(b * NKV + kvh) * HD + row) * S_LEN + j0 + s_c8,
                    lv + r * 4096);
        }
    };

    const int kstart = (q0 >= WIN) ? (q0 - WIN) : 0;
    stage(kstart, 0);
    int buf = 0;

    char* prow = (char*)(&ldsP[wave][l16][0]);

    for (int j0 = kstart; j0 <= q0; j0 += 64) {
        __syncthreads();                              // drains DMA into [buf]
        if (j0 + 64 <= q0) stage(j0 + 64, buf ^ 1);   // async, lands by next barrier

        // S^T = K @ Q^T
        f32x4 sacc[4] = {};
#pragma unroll
        for (int t = 0; t < 4; ++t) {
            const __hip_bfloat16* krow = &ldsK[buf][t * 16 + l16][0];
            short8 bk0 = *reinterpret_cast<const short8*>(krow + ((quad ^ sw) * 8));
            short8 bk1 = *reinterpret_cast<const short8*>(krow + (((4 + quad) ^ sw) * 8));
            sacc[t] = __builtin_amdgcn_mfma_f32_16x16x32_bf16(bk0, aq[0], sacc[t], 0, 0, 0);
            sacc[t] = __builtin_amdgcn_mfma_f32_16x16x32_bf16(bk1, aq[1], sacc[t], 0, 0, 0);
        }

        const bool need_mask = (j0 == q0) || (q0 >= WIN && j0 == kstart);
        float sv[4][4];
        if (need_mask) {
#pragma unroll
            for (int t = 0; t < 4; ++t)
#pragma unroll
                for (int r = 0; r < 4; ++r) {
                    int j = j0 + t * 16 + quad * 4 + r;
                    bool ok = (j <= qi) && (j + WIN >= qi);
                    sv[t][r] = ok ? sacc[t][r] * SL2 : -1e30f;
                }
        } else {
#pragma unroll
            for (int t = 0; t < 4; ++t)
#pragma unroll
                for (int r = 0; r < 4; ++r) sv[t][r] = sacc[t][r] * SL2;
        }
        // online softmax (exp2 domain): in-lane reduce + 2 shuffles
        float cm = -1e30f;
#pragma unroll
        for (int t = 0; t < 4; ++t)
#pragma unroll
            for (int r = 0; r < 4; ++r) cm = fmaxf(cm, sv[t][r]);
        cm = fmaxf(cm, __shfl_xor(cm, 16));
        cm = fmaxf(cm, __shfl_xor(cm, 32));
        float mn = fmaxf(m, cm);
        float alpha = exp2f(m - mn);
        m = mn;
        float sp = 0.f;
#pragma unroll
        for (int t = 0; t < 4; ++t)
#pragma unroll
            for (int r = 0; r < 4; ++r) { sv[t][r] = exp2f(sv[t][r] - mn); sp += sv[t][r]; }
        sp += __shfl_xor(sp, 16);
        sp += __shfl_xor(sp, 32);
        l = l * alpha + sp;
#pragma unroll
        for (int t = 0; t < 4; ++t)
#pragma unroll
            for (int r = 0; r < 4; ++r) acc_o[t][r] *= alpha;
        // P^T -> LDS (XOR unit swizzle; wave-private, in-order)
#pragma unroll
        for (int t = 0; t < 4; ++t) {
            alignas(8) __hip_bfloat16 hp[4];
#pragma unroll
            for (int r = 0; r < 4; ++r) hp[r] = __float2bfloat16(sv[t][r]);
            int swb = ((((2 * t + (quad >> 1)) ^ (l16 & 7)) << 4) | ((quad & 1) << 3));
            *reinterpret_cast<ushort4*>(prow + swb) = *reinterpret_cast<ushort4*>(hp);
        }

        // O^T += VT @ P^T
#pragma unroll
        for (int ks = 0; ks < 2; ++ks) {
            short8 pf = *reinterpret_cast<const short8*>(
                prow + (((4 * ks + quad) ^ (l16 & 7)) << 4));
#pragma unroll
            for (int t = 0; t < 4; ++t) {
                const __hip_bfloat16* vrow = &ldsVT[buf][t * 16 + l16][0];
                short8 vf = *reinterpret_cast<const short8*>(
                    vrow + (((ks * 4 + quad) ^ sw) * 8));
                acc_o[t] = __builtin_amdgcn_mfma_f32_16x16x32_bf16(vf, pf, acc_o[t], 0, 0, 0);
            }
        }
        buf ^= 1;
    }

    {
        float inv = 1.f / l;
        __hip_bfloat16* op =
            O + (size_t)(b * S_LEN + qi) * (NH * HD) + h * HD;
#pragma unroll
        for (int t = 0; t < 4; ++t) {
            alignas(8) __hip_bfloat16 ho[4];
#pragma unroll
            for (int r = 0; r < 4; ++r) ho[r] = __float2bfloat16(acc_o[t][r] * inv);
            *reinterpret_cast<ushort4*>(op + t * 16 + quad * 4) =
                *reinterpret_cast<ushort4*>(ho);
        }
    }
}

// ---------------- launch ----------------
extern "C" void kernel_launch(void* const* d_in, const int* in_sizes, int n_in,
                              void* d_out, int out_size, void* d_ws, size_t ws_size,
                              hipStream_t stream) {
    const float* X  = (const float*)d_in[0];
    const float* Wq = (const float*)d_in[1];
    const float* Wk = (const float*)d_in[2];
    const float* Wv = (const float*)d_in[3];
    const float* Wo = (const float*)d_in[4];
    float* out = (float*)d_out;

    const int ROWS = 2 * S_LEN;               // 4096
    char* ws = (char*)d_ws;
    size_t off = 0;
    __hip_bfloat16* Xb     = (__hip_bfloat16*)(ws + off); off += (size_t)ROWS * DMODEL * 2;
    __hip_bfloat16* WqkvT  = (__hip_bfloat16*)(ws + off); off += (size_t)2048 * DMODEL * 2;
    __hip_bfloat16* WoT    = (__hip_bfloat16*)(ws + off); off += (size_t)DMODEL * DMODEL * 2;
    __hip_bfloat16* Qb     = (__hip_bfloat16*)(ws + off); off += (size_t)ROWS * (NH * HD) * 2;
    __hip_bfloat16* Kb     = (__hip_bfloat16*)(ws + off); off += (size_t)ROWS * (NKV * HD) * 2;
    __hip_bfloat16* VTg    = (__hip_bfloat16*)(ws + off); off += (size_t)ROWS * (NKV * HD) * 2;
    __hip_bfloat16* Ob     = (__hip_bfloat16*)(ws + off); off += (size_t)ROWS * (NH * HD) * 2;

    // 1. cast X; fused transpose of all weights
    cast_bf16_kernel<<<(ROWS * DMODEL) / (256 * 4), 256, 0, stream>>>(X, Xb, ROWS * DMODEL);
    transpose_cast4_kernel<<<dim3(32, 32, 4), dim3(32, 8), 0, stream>>>(
        Wq, Wk, Wv, Wo, WqkvT, WoT);

    // 2. fused QKV projection + RoPE + V transpose (1024 blocks, 4/CU)
    gemm128_kernel<0><<<dim3(2048 / 64, ROWS / 128), 128, 0, stream>>>(
        Xb, WqkvT, Qb, Kb, VTg, 2048, DMODEL);

    // 3. MFMA flash attention (head-split, 1024 blocks, 4/CU)
    attn_mfma_kernel<<<dim3(S_LEN / 64, NH, 2), 256, 0, stream>>>(Qb, Kb, VTg, Ob);

    // 4. output projection -> fp32 (512 blocks, 2/CU)
    gemm128_kernel<1><<<dim3(DMODEL / 64, ROWS / 128), 128, 0, stream>>>(
        Ob, WoT, out, nullptr, nullptr, DMODEL, DMODEL);
}

// Round 2
// 158.529 us; speedup vs baseline: 1.0498x; 1.0215x over previous
//
#include <hip/hip_runtime.h>
#include <hip/hip_bf16.h>

typedef __attribute__((ext_vector_type(8))) short short8;
typedef __attribute__((ext_vector_type(4))) float f32x4;

#define S_LEN 2048
#define NH 16
#define NKV 8
#define HD 64
#define WIN 512
#define DMODEL 1024
#define LOG2_10000 13.287712379549449f

// async 16B global -> LDS (wave-uniform LDS base + lane*16 semantics)
#define GLOAD16(g, l)                                                        \
    __builtin_amdgcn_global_load_lds(                                        \
        (const __attribute__((address_space(1))) unsigned int*)(g),          \
        (__attribute__((address_space(3))) unsigned int*)(l), 16, 0, 0)

// ------- prep: fused X-cast (z=4) + transpose+cast of 4 weights (z=0..3) ----
// ROUND 15: cast kernel folded in as a 5th z-slice — one fewer serialized
// launch in the graph.
__global__ void prep_kernel(const float* __restrict__ X,
                            const float* __restrict__ W0,
                            const float* __restrict__ W1,
                            const float* __restrict__ W2,
                            const float* __restrict__ W3,
                            __hip_bfloat16* __restrict__ Xb,
                            __hip_bfloat16* __restrict__ WqkvT,
                            __hip_bfloat16* __restrict__ WoT) {
    if (blockIdx.z == 4) {                         // X cast: fp32 -> bf16
        int tid = (blockIdx.y * 32 + blockIdx.x) * 256 + threadIdx.y * 32 + threadIdx.x;
        const float4* Xi = reinterpret_cast<const float4*>(X);
#pragma unroll
        for (int r = 0; r < 4; ++r) {
            int i = tid + r * (1024 * 256);        // float4 index
            float4 v = Xi[i];
            alignas(8) __hip_bfloat16 h[4];
            h[0] = __float2bfloat16(v.x);
            h[1] = __float2bfloat16(v.y);
            h[2] = __float2bfloat16(v.z);
            h[3] = __float2bfloat16(v.w);
            *reinterpret_cast<ushort4*>(Xb + (size_t)i * 4) =
                *reinterpret_cast<ushort4*>(h);
        }
        return;
    }
    __shared__ float tile[32][33];
    const int K = DMODEL;
    const float* W;
    __hip_bfloat16* WT;
    int N;
    switch (blockIdx.z) {
        case 0: W = W0; WT = WqkvT;                          N = 1024; break;
        case 1: W = W1; WT = WqkvT + (size_t)1024 * K;       N = 512;  break;
        case 2: W = W2; WT = WqkvT + (size_t)1536 * K;       N = 512;  break;
        default: W = W3; WT = WoT;                           N = 1024; break;
    }
    if ((int)blockIdx.x * 32 >= N) return;
    int nx = blockIdx.x * 32 + threadIdx.x;
    int k0 = blockIdx.y * 32;
#pragma unroll
    for (int r = 0; r < 4; ++r) {
        int k = k0 + threadIdx.y + r * 8;
        tile[threadIdx.y + r * 8][threadIdx.x] = W[(size_t)k * N + nx];
    }
    __syncthreads();
#pragma unroll
    for (int r = 0; r < 4; ++r) {
        int nn = blockIdx.x * 32 + threadIdx.y + r * 8;
        int kk = k0 + threadIdx.x;
        WT[(size_t)nn * K + kk] = __float2bfloat16(tile[threadIdx.x][threadIdx.y + r * 8]);
    }
}

// ------------- GEMM: 128(M)x64(N) tile, 256 thr = 4 waves, DMA dbuf -----------
// ROUND 15: r13/r14 ran this tile with 128 threads (2 waves): QKV 8 waves/CU
// (2/SIMD), out-proj 4 waves/CU (1/SIMD) — nothing to co-schedule during the
// per-K-step vmcnt drain (m233: ~72% of 2-phase critical path; m114: hiding
// comes from co-resident independent waves). Same tile/LDS/grid, re-warped to
// 4 waves x (32 rows x 64 cols), acc[2][4] = 32 VGPR -> fits the 128-VGPR cap
// for 4 waves/SIMD. QKV: 16 waves/CU, out-proj: 8 waves/CU.
// MODE 0: fused QKV epilogue, in-register RoPE on Q/K (__cosf/__sinf ONLY —
//         libm calls spill the acc array). MODE 1: fp32 C.
template <int MODE>
__global__ __launch_bounds__(256, 4) void gemm128_kernel(
    const __hip_bfloat16* __restrict__ A,
    const __hip_bfloat16* __restrict__ BT,
    void* __restrict__ o0, void* __restrict__ o1, void* __restrict__ o2,
    int N, int K) {
    __shared__ __hip_bfloat16 ldsA[2][128 * 32];   // 16 KB
    __shared__ __hip_bfloat16 ldsB[2][64 * 32];    // 8 KB
    const int tx = threadIdx.x;
    const int wave = tx >> 6;
    const int lane = tx & 63;
    const int l16 = lane & 15;
    const int quad = lane >> 4;
    const int col0 = blockIdx.x * 64;
    const int row0 = blockIdx.y * 128;
    const int wrow = wave * 32;

    f32x4 acc[2][4] = {};

    const int arow = tx >> 2;            // 0..63
    const int kc8 = (tx & 3) * 8;
    const __hip_bfloat16* gA = A + (size_t)(row0 + arow) * K + kc8;
    const __hip_bfloat16* gB = BT + (size_t)(col0 + arow) * K + kc8;

    auto stage = [&](int k0, int bf) {
        char* lA = (char*)(&ldsA[bf][0]) + tx * 16;
        char* lB = (char*)(&ldsB[bf][0]) + tx * 16;
        GLOAD16(gA + k0, lA);                       // A rows 0..63
        GLOAD16(gA + (size_t)64 * K + k0, lA + 4096);  // A rows 64..127
        GLOAD16(gB + k0, lB);                       // B rows 0..63
    };

    stage(0, 0);
    int buf = 0;
    for (int k0 = 0; k0 < K; k0 += 32) {
        __syncthreads();                            // drains DMA into [buf]
        if (k0 + 32 < K) stage(k0 + 32, buf ^ 1);   // lands by next barrier
        short8 af[2], bf4[4];
#pragma unroll
        for (int i = 0; i < 2; ++i)
            af[i] = *reinterpret_cast<const short8*>(
                &ldsA[buf][0] + (wrow + i * 16 + l16) * 32 + quad * 8);
#pragma unroll
        for (int i = 0; i < 4; ++i)
            bf4[i] = *reinterpret_cast<const short8*>(
                &ldsB[buf][0] + (i * 16 + l16) * 32 + quad * 8);
#pragma unroll
        for (int mi = 0; mi < 2; ++mi)
#pragma unroll
            for (int ni = 0; ni < 4; ++ni)
                acc[mi][ni] = __builtin_amdgcn_mfma_f32_16x16x32_bf16(
                    af[mi], bf4[ni], acc[mi][ni], 0, 0, 0);
        buf ^= 1;
    }

    const int rbase = row0 + wrow;
    if (MODE == 0) {
        const int cbaseg = col0;                    // 64-aligned global col
        const bool isQ = (cbaseg < DMODEL);
        const bool isK = (cbaseg >= DMODEL) && (cbaseg < DMODEL + 512);
        if (isQ || isK) {
            float invf[2];
            invf[0] = exp2f(-(float)(l16)      * (LOG2_10000 / 32.0f));
            invf[1] = exp2f(-(float)(16 + l16) * (LOG2_10000 / 32.0f));
#pragma unroll
            for (int mi = 0; mi < 2; ++mi)
#pragma unroll
                for (int r = 0; r < 4; ++r) {
                    int srow = (rbase + mi * 16 + quad * 4 + r) & (S_LEN - 1);
#pragma unroll
                    for (int ni = 0; ni < 2; ++ni) {
                        float ang = (float)srow * invf[ni];
                        float c = __cosf(ang), s = __sinf(ang);
                        float x1 = acc[mi][ni][r], x2 = acc[mi][ni + 2][r];
                        acc[mi][ni][r]     = x1 * c - x2 * s;
                        acc[mi][ni + 2][r] = x2 * c + x1 * s;
                    }
                }
            __hip_bfloat16* Co = (__hip_bfloat16*)(isQ ? o0 : o1);
            int cbase = isQ ? cbaseg : cbaseg - DMODEL;
            int rowstride = isQ ? (NH * HD) : (NKV * HD);
#pragma unroll
            for (int mi = 0; mi < 2; ++mi)
#pragma unroll
                for (int ni = 0; ni < 4; ++ni) {
                    size_t col = cbase + ni * 16 + l16;
#pragma unroll
                    for (int r = 0; r < 4; ++r)
                        Co[(size_t)(rbase + mi * 16 + quad * 4 + r) * rowstride + col] =
                            __float2bfloat16(acc[mi][ni][r]);
                }
        } else {                                   // V region -> transposed VT
            __hip_bfloat16* VTo = (__hip_bfloat16*)o2;
            int bb = row0 >> 11;
#pragma unroll
            for (int mi = 0; mi < 2; ++mi) {
                int s = ((rbase + mi * 16 + quad * 4) & (S_LEN - 1));
#pragma unroll
                for (int ni = 0; ni < 4; ++ni) {
                    int colv = cbaseg - 1536 + ni * 16 + l16;   // 0..511
                    int vh = colv >> 6, d = colv & 63;
                    alignas(8) __hip_bfloat16 hv[4];
#pragma unroll
                    for (int r = 0; r < 4; ++r) hv[r] = __float2bfloat16(acc[mi][ni][r]);
                    *reinterpret_cast<ushort4*>(
                        VTo + ((size_t)(bb * NKV + vh) * HD + d) * S_LEN + s) =
                        *reinterpret_cast<ushort4*>(hv);
                }
            }
        }
    } else {                                       // fp32 C
        float* Co = (float*)o0;
#pragma unroll
        for (int mi = 0; mi < 2; ++mi)
#pragma unroll
            for (int ni = 0; ni < 4; ++ni) {
                size_t col = col0 + ni * 16 + l16;
#pragma unroll
                for (int r = 0; r < 4; ++r)
                    Co[(size_t)(rbase + mi * 16 + quad * 4 + r) * N + col] = acc[mi][ni][r];
            }
    }
}

// ---------------- MFMA flash attention: head-split, DMA dbuf, swizzled ----
// ROUND 14: head-split, grid (32,16,2)=1024, 40 KB LDS -> 4 blocks/CU.
// ROUND 15: + T13 defer-max (skip alpha-rescale when per-tile max growth
// <= 8 in exp2 domain; P bounded by 256, fine in bf16/f32 — m214v23/m239).
__global__ __launch_bounds__(256, 4) void attn_mfma_kernel(
    const __hip_bfloat16* __restrict__ Q,
    const __hip_bfloat16* __restrict__ K,
    const __hip_bfloat16* __restrict__ VT,
    __hip_bfloat16* __restrict__ O) {
    __shared__ __hip_bfloat16 ldsK[2][64][64];       // 16 KB
    __shared__ __hip_bfloat16 ldsVT[2][64][64];      // 16 KB
    __shared__ __hip_bfloat16 ldsP[4][16][64];       // 8 KB, XOR unit swizzle
    const int tx = threadIdx.x;
    const int wave = tx >> 6;
    const int lane = tx & 63;
    const int l16 = lane & 15;
    const int quad = lane >> 4;
    const int q0 = blockIdx.x * 64;
    const int h = blockIdx.y;
    const int kvh = h >> 1;
    const int b = blockIdx.z;
    const int qi = q0 + wave * 16 + l16;

    short8 aq[2];
    {
        const __hip_bfloat16* qp =
            Q + (size_t)(b * S_LEN + qi) * (NH * HD) + h * HD + quad * 8;
        aq[0] = *reinterpret_cast<const short8*>(qp);
        aq[1] = *reinterpret_cast<const short8*>(qp + 32);
    }
    f32x4 acc_o[4] = {};
    float m = -1e30f, l = 0.f;
    const float SL2 = 0.125f * 1.4426950408889634f;   // scale * log2(e)

    // staging: row = tx>>3 (+32), chunk-in-row = tx&7, XOR source swizzle
    const int s_row = tx >> 3;
    const int s_c8 = (((tx & 7) ^ (s_row & 7))) * 8;
    const int sw = (l16 & 7);                          // reader swizzle key
    auto stage = [&](int j0, int bf) {
        char* lk = (char*)(&ldsK[bf][0][0]) + tx * 16;
        char* lv = (char*)(&ldsVT[bf][0][0]) + tx * 16;
#pragma unroll
        for (int r = 0; r < 2; ++r) {
            int row = s_row + r * 32;
            GLOAD16(K + (size_t)(b * S_LEN + j0 + row) * (NKV * HD) + kvh * HD + s_c8,
                    lk + r * 4096);
            GLOAD16(VT + ((size_t)(b * NKV + kvh) * HD + row) * S_LEN + j0 + s_c8,
                    lv + r * 4096);
        }
    };

    const int kstart = (q0 >= WIN) ? (q0 - WIN) : 0;
    stage(kstart, 0);
    int buf = 0;

    char* prow = (char*)(&ldsP[wave][l16][0]);

    for (int j0 = kstart; j0 <= q0; j0 += 64) {
        __syncthreads();                              // drains DMA into [buf]
        if (j0 + 64 <= q0) stage(j0 + 64, buf ^ 1);   // async, lands by next barrier

        // S^T = K @ Q^T
        f32x4 sacc[4] = {};
#pragma unroll
        for (int t = 0; t < 4; ++t) {
            const __hip_bfloat16* krow = &ldsK[buf][t * 16 + l16][0];
            short8 bk0 = *reinterpret_cast<const short8*>(krow + ((quad ^ sw) * 8));
            short8 bk1 = *reinterpret_cast<const short8*>(krow + (((4 + quad) ^ sw) * 8));
            sacc[t] = __builtin_amdgcn_mfma_f32_16x16x32_bf16(bk0, aq[0], sacc[t], 0, 0, 0);
            sacc[t] = __builtin_amdgcn_mfma_f32_16x16x32_bf16(bk1, aq[1], sacc[t], 0, 0, 0);
        }

        const bool need_mask = (j0 == q0) || (q0 >= WIN && j0 == kstart);
        float sv[4][4];
        if (need_mask) {
#pragma unroll
            for (int t = 0; t < 4; ++t)
#pragma unroll
                for (int r = 0; r < 4; ++r) {
                    int j = j0 + t * 16 + quad * 4 + r;
                    bool ok = (j <= qi) && (j + WIN >= qi);
                    sv[t][r] = ok ? sacc[t][r] * SL2 : -1e30f;
                }
        } else {
#pragma unroll
            for (int t = 0; t < 4; ++t)
#pragma unroll
                for (int r = 0; r < 4; ++r) sv[t][r] = sacc[t][r] * SL2;
        }
        // online softmax (exp2 domain): in-lane reduce + 2 shuffles
        float cm = -1e30f;
#pragma unroll
        for (int t = 0; t < 4; ++t)
#pragma unroll
            for (int r = 0; r < 4; ++r) cm = fmaxf(cm, sv[t][r]);
        cm = fmaxf(cm, __shfl_xor(cm, 16));
        cm = fmaxf(cm, __shfl_xor(cm, 32));
        // T13 defer-max: skip rescale while the tile max stays within 8
        // (exp2 domain) of the running max; P then bounded by 2^8 = 256.
        if (!__all(cm - m <= 8.0f)) {
            float mn = fmaxf(m, cm);
            float alpha = exp2f(m - mn);
            m = mn;
            l *= alpha;
#pragma unroll
            for (int t = 0; t < 4; ++t)
#pragma unroll
                for (int r = 0; r < 4; ++r) acc_o[t][r] *= alpha;
        }
        float sp = 0.f;
#pragma unroll
        for (int t = 0; t < 4; ++t)
#pragma unroll
            for (int r = 0; r < 4; ++r) { sv[t][r] = exp2f(sv[t][r] - m); sp += sv[t][r]; }
        sp += __shfl_xor(sp, 16);
        sp += __shfl_xor(sp, 32);
        l += sp;
        // P^T -> LDS (XOR unit swizzle; wave-private, in-order)
#pragma unroll
        for (int t = 0; t < 4; ++t) {
            alignas(8) __hip_bfloat16 hp[4];
#pragma unroll
            for (int r = 0; r < 4; ++r) hp[r] = __float2bfloat16(sv[t][r]);
            int swb = ((((2 * t + (quad >> 1)) ^ (l16 & 7)) << 4) | ((quad & 1) << 3));
            *reinterpret_cast<ushort4*>(prow + swb) = *reinterpret_cast<ushort4*>(hp);
        }

        // O^T += VT @ P^T
#pragma unroll
        for (int ks = 0; ks < 2; ++ks) {
            short8 pf = *reinterpret_cast<const short8*>(
                prow + (((4 * ks + quad) ^ (l16 & 7)) << 4));
#pragma unroll
            for (int t = 0; t < 4; ++t) {
                const __hip_bfloat16* vrow = &ldsVT[buf][t * 16 + l16][0];
                short8 vf = *reinterpret_cast<const short8*>(
                    vrow + (((ks * 4 + quad) ^ sw) * 8));
                acc_o[t] = __builtin_amdgcn_mfma_f32_16x16x32_bf16(vf, pf, acc_o[t], 0, 0, 0);
            }
        }
        buf ^= 1;
    }

    {
        float inv = 1.f / l;
        __hip_bfloat16* op =
            O + (size_t)(b * S_LEN + qi) * (NH * HD) + h * HD;
#pragma unroll
        for (int t = 0; t < 4; ++t) {
            alignas(8) __hip_bfloat16 ho[4];
#pragma unroll
            for (int r = 0; r < 4; ++r) ho[r] = __float2bfloat16(acc_o[t][r] * inv);
            *reinterpret_cast<ushort4*>(op + t * 16 + quad * 4) =
                *reinterpret_cast<ushort4*>(ho);
        }
    }
}

// ---------------- launch ----------------
extern "C" void kernel_launch(void* const* d_in, const int* in_sizes, int n_in,
                              void* d_out, int out_size, void* d_ws, size_t ws_size,
                              hipStream_t stream) {
    const float* X  = (const float*)d_in[0];
    const float* Wq = (const float*)d_in[1];
    const float* Wk = (const float*)d_in[2];
    const float* Wv = (const float*)d_in[3];
    const float* Wo = (const float*)d_in[4];
    float* out = (float*)d_out;

    const int ROWS = 2 * S_LEN;               // 4096
    char* ws = (char*)d_ws;
    size_t off = 0;
    __hip_bfloat16* Xb     = (__hip_bfloat16*)(ws + off); off += (size_t)ROWS * DMODEL * 2;
    __hip_bfloat16* WqkvT  = (__hip_bfloat16*)(ws + off); off += (size_t)2048 * DMODEL * 2;
    __hip_bfloat16* WoT    = (__hip_bfloat16*)(ws + off); off += (size_t)DMODEL * DMODEL * 2;
    __hip_bfloat16* Qb     = (__hip_bfloat16*)(ws + off); off += (size_t)ROWS * (NH * HD) * 2;
    __hip_bfloat16* Kb     = (__hip_bfloat16*)(ws + off); off += (size_t)ROWS * (NKV * HD) * 2;
    __hip_bfloat16* VTg    = (__hip_bfloat16*)(ws + off); off += (size_t)ROWS * (NKV * HD) * 2;
    __hip_bfloat16* Ob     = (__hip_bfloat16*)(ws + off); off += (size_t)ROWS * (NH * HD) * 2;

    // 1. fused prep: X cast (z=4) + all weight transposes (z=0..3)
    prep_kernel<<<dim3(32, 32, 5), dim3(32, 8), 0, stream>>>(
        X, Wq, Wk, Wv, Wo, Xb, WqkvT, WoT);

    // 2. fused QKV projection + RoPE + V transpose (1024 blocks, 4/CU, 16 w/CU)
    gemm128_kernel<0><<<dim3(2048 / 64, ROWS / 128), 256, 0, stream>>>(
        Xb, WqkvT, Qb, Kb, VTg, 2048, DMODEL);

    // 3. MFMA flash attention (head-split, 1024 blocks, 4/CU)
    attn_mfma_kernel<<<dim3(S_LEN / 64, NH, 2), 256, 0, stream>>>(Qb, Kb, VTg, Ob);

    // 4. output projection -> fp32 (512 blocks, 2/CU, 8 w/CU)
    gemm128_kernel<1><<<dim3(DMODEL / 64, ROWS / 128), 256, 0, stream>>>(
        Ob, WoT, out, nullptr, nullptr, DMODEL, DMODEL);
}

// Round 3
// 154.502 us; speedup vs baseline: 1.0772x; 1.0261x over previous
//
#include <hip/hip_runtime.h>
#include <hip/hip_bf16.h>

typedef __attribute__((ext_vector_type(8))) short short8;
typedef __attribute__((ext_vector_type(4))) float f32x4;

#define S_LEN 2048
#define NH 16
#define NKV 8
#define HD 64
#define WIN 512
#define DMODEL 1024
#define LOG2_10000 13.287712379549449f

// async 16B global -> LDS (wave-uniform LDS base + lane*16 semantics)
#define GLOAD16(g, l)                                                        \
    __builtin_amdgcn_global_load_lds(                                        \
        (const __attribute__((address_space(1))) unsigned int*)(g),          \
        (__attribute__((address_space(3))) unsigned int*)(l), 16, 0, 0)

// ------- prep: fused X-cast (z=4) + transpose+cast of 4 weights (z=0..3) ----
__global__ void prep_kernel(const float* __restrict__ X,
                            const float* __restrict__ W0,
                            const float* __restrict__ W1,
                            const float* __restrict__ W2,
                            const float* __restrict__ W3,
                            __hip_bfloat16* __restrict__ Xb,
                            __hip_bfloat16* __restrict__ WqkvT,
                            __hip_bfloat16* __restrict__ WoT) {
    if (blockIdx.z == 4) {                         // X cast: fp32 -> bf16
        int tid = (blockIdx.y * 32 + blockIdx.x) * 256 + threadIdx.y * 32 + threadIdx.x;
        const float4* Xi = reinterpret_cast<const float4*>(X);
#pragma unroll
        for (int r = 0; r < 4; ++r) {
            int i = tid + r * (1024 * 256);        // float4 index
            float4 v = Xi[i];
            alignas(8) __hip_bfloat16 h[4];
            h[0] = __float2bfloat16(v.x);
            h[1] = __float2bfloat16(v.y);
            h[2] = __float2bfloat16(v.z);
            h[3] = __float2bfloat16(v.w);
            *reinterpret_cast<ushort4*>(Xb + (size_t)i * 4) =
                *reinterpret_cast<ushort4*>(h);
        }
        return;
    }
    __shared__ float tile[32][33];
    const int K = DMODEL;
    const float* W;
    __hip_bfloat16* WT;
    int N;
    switch (blockIdx.z) {
        case 0: W = W0; WT = WqkvT;                          N = 1024; break;
        case 1: W = W1; WT = WqkvT + (size_t)1024 * K;       N = 512;  break;
        case 2: W = W2; WT = WqkvT + (size_t)1536 * K;       N = 512;  break;
        default: W = W3; WT = WoT;                           N = 1024; break;
    }
    if ((int)blockIdx.x * 32 >= N) return;
    int nx = blockIdx.x * 32 + threadIdx.x;
    int k0 = blockIdx.y * 32;
#pragma unroll
    for (int r = 0; r < 4; ++r) {
        int k = k0 + threadIdx.y + r * 8;
        tile[threadIdx.y + r * 8][threadIdx.x] = W[(size_t)k * N + nx];
    }
    __syncthreads();
#pragma unroll
    for (int r = 0; r < 4; ++r) {
        int nn = blockIdx.x * 32 + threadIdx.y + r * 8;
        int kk = k0 + threadIdx.x;
        WT[(size_t)nn * K + kk] = __float2bfloat16(tile[threadIdx.x][threadIdx.y + r * 8]);
    }
}

// ------------- GEMM: 128(M)x64(N) tile, 256 thr = 4 waves, BK=64, DMA dbuf ---
// ROUND 16: r15 had BK=32 -> 32 barrier+vmcnt-drain events per block (m233:
// that overhead is ~72% of the 2-phase critical path) with only 8 MFMA/wave
// between barriers. BK=64: 16 iterations, 16 MFMA/wave per phase — each drain
// amortized over 2x compute. LDS 24->48 KB (3 blocks/CU QKV).
// [128][64] rows are 128 B => raw ds_read_b128 would 16-way bank-conflict
// (G4); global_load_lds writes linearly, so per rule #21 the fix is the
// both-sides involution: XOR the GLOBAL source chunk with (row&7) at stage
// time, XOR the ds_read chunk with (row&7)=(l16&7) at read time — identical
// pattern to the attention kernel's verified K/VT staging.
// MODE 0: fused QKV epilogue, in-register RoPE on Q/K (__cosf/__sinf ONLY —
//         libm calls spill the acc array). MODE 1: fp32 C.
template <int MODE>
__global__ __launch_bounds__(256, 4) void gemm128_kernel(
    const __hip_bfloat16* __restrict__ A,
    const __hip_bfloat16* __restrict__ BT,
    void* __restrict__ o0, void* __restrict__ o1, void* __restrict__ o2,
    int N, int K) {
    __shared__ __hip_bfloat16 ldsA[2][128 * 64];   // 32 KB
    __shared__ __hip_bfloat16 ldsB[2][64 * 64];    // 16 KB
    const int tx = threadIdx.x;
    const int wave = tx >> 6;
    const int lane = tx & 63;
    const int l16 = lane & 15;
    const int quad = lane >> 4;
    const int col0 = blockIdx.x * 64;
    const int row0 = blockIdx.y * 128;
    const int wrow = wave * 32;
    const int sw = l16 & 7;                        // reader swizzle key

    f32x4 acc[2][4] = {};

    // staging: row = tx>>3 (0..31), chunk = tx&7, XOR source swizzle
    const int arow = tx >> 3;
    const int cs8 = ((tx & 7) ^ (arow & 7)) * 8;   // swizzled source chunk
    const __hip_bfloat16* gA = A + (size_t)(row0 + arow) * K + cs8;
    const __hip_bfloat16* gB = BT + (size_t)(col0 + arow) * K + cs8;

    auto stage = [&](int k0, int bf) {
        char* lA = (char*)(&ldsA[bf][0]) + tx * 16;
        char* lB = (char*)(&ldsB[bf][0]) + tx * 16;
#pragma unroll
        for (int r = 0; r < 4; ++r)                // A rows r*32 .. r*32+31
            GLOAD16(gA + (size_t)(r * 32) * K + k0, lA + r * 4096);
#pragma unroll
        for (int r = 0; r < 2; ++r)                // B rows r*32 .. r*32+31
            GLOAD16(gB + (size_t)(r * 32) * K + k0, lB + r * 4096);
    };

    stage(0, 0);
    int buf = 0;
    for (int k0 = 0; k0 < K; k0 += 64) {
        __syncthreads();                            // drains DMA into [buf]
        if (k0 + 64 < K) stage(k0 + 64, buf ^ 1);   // lands by next barrier
        short8 af[2][2], bf4[4][2];
#pragma unroll
        for (int i = 0; i < 2; ++i) {
            const char* ar = (const char*)(&ldsA[buf][0]) + (wrow + i * 16 + l16) * 128;
#pragma unroll
            for (int ks = 0; ks < 2; ++ks)
                af[i][ks] = *reinterpret_cast<const short8*>(
                    ar + (((ks * 4 + quad) ^ sw) << 4));
        }
#pragma unroll
        for (int i = 0; i < 4; ++i) {
            const char* br = (const char*)(&ldsB[buf][0]) + (i * 16 + l16) * 128;
#pragma unroll
            for (int ks = 0; ks < 2; ++ks)
                bf4[i][ks] = *reinterpret_cast<const short8*>(
                    br + (((ks * 4 + quad) ^ sw) << 4));
        }
#pragma unroll
        for (int ks = 0; ks < 2; ++ks)
#pragma unroll
            for (int mi = 0; mi < 2; ++mi)
#pragma unroll
                for (int ni = 0; ni < 4; ++ni)
                    acc[mi][ni] = __builtin_amdgcn_mfma_f32_16x16x32_bf16(
                        af[mi][ks], bf4[ni][ks], acc[mi][ni], 0, 0, 0);
        buf ^= 1;
    }

    const int rbase = row0 + wrow;
    if (MODE == 0) {
        const int cbaseg = col0;                    // 64-aligned global col
        const bool isQ = (cbaseg < DMODEL);
        const bool isK = (cbaseg >= DMODEL) && (cbaseg < DMODEL + 512);
        if (isQ || isK) {
            float invf[2];
            invf[0] = exp2f(-(float)(l16)      * (LOG2_10000 / 32.0f));
            invf[1] = exp2f(-(float)(16 + l16) * (LOG2_10000 / 32.0f));
#pragma unroll
            for (int mi = 0; mi < 2; ++mi)
#pragma unroll
                for (int r = 0; r < 4; ++r) {
                    int srow = (rbase + mi * 16 + quad * 4 + r) & (S_LEN - 1);
#pragma unroll
                    for (int ni = 0; ni < 2; ++ni) {
                        float ang = (float)srow * invf[ni];
                        float c = __cosf(ang), s = __sinf(ang);
                        float x1 = acc[mi][ni][r], x2 = acc[mi][ni + 2][r];
                        acc[mi][ni][r]     = x1 * c - x2 * s;
                        acc[mi][ni + 2][r] = x2 * c + x1 * s;
                    }
                }
            __hip_bfloat16* Co = (__hip_bfloat16*)(isQ ? o0 : o1);
            int cbase = isQ ? cbaseg : cbaseg - DMODEL;
            int rowstride = isQ ? (NH * HD) : (NKV * HD);
#pragma unroll
            for (int mi = 0; mi < 2; ++mi)
#pragma unroll
                for (int ni = 0; ni < 4; ++ni) {
                    size_t col = cbase + ni * 16 + l16;
#pragma unroll
                    for (int r = 0; r < 4; ++r)
                        Co[(size_t)(rbase + mi * 16 + quad * 4 + r) * rowstride + col] =
                            __float2bfloat16(acc[mi][ni][r]);
                }
        } else {                                   // V region -> transposed VT
            __hip_bfloat16* VTo = (__hip_bfloat16*)o2;
            int bb = row0 >> 11;
#pragma unroll
            for (int mi = 0; mi < 2; ++mi) {
                int s = ((rbase + mi * 16 + quad * 4) & (S_LEN - 1));
#pragma unroll
                for (int ni = 0; ni < 4; ++ni) {
                    int colv = cbaseg - 1536 + ni * 16 + l16;   // 0..511
                    int vh = colv >> 6, d = colv & 63;
                    alignas(8) __hip_bfloat16 hv[4];
#pragma unroll
                    for (int r = 0; r < 4; ++r) hv[r] = __float2bfloat16(acc[mi][ni][r]);
                    *reinterpret_cast<ushort4*>(
                        VTo + ((size_t)(bb * NKV + vh) * HD + d) * S_LEN + s) =
                        *reinterpret_cast<ushort4*>(hv);
                }
            }
        }
    } else {                                       // fp32 C
        float* Co = (float*)o0;
#pragma unroll
        for (int mi = 0; mi < 2; ++mi)
#pragma unroll
            for (int ni = 0; ni < 4; ++ni) {
                size_t col = col0 + ni * 16 + l16;
#pragma unroll
                for (int r = 0; r < 4; ++r)
                    Co[(size_t)(rbase + mi * 16 + quad * 4 + r) * N + col] = acc[mi][ni][r];
            }
    }
}

// ---------------- MFMA flash attention: head-split, DMA dbuf, swizzled ----
// ROUND 14: head-split, grid (32,16,2)=1024, 40 KB LDS -> 4 blocks/CU.
// ROUND 15: + T13 defer-max (skip alpha-rescale when per-tile max growth
// <= 8 in exp2 domain; P bounded by 256, fine in bf16/f32 — m214v23/m239).
__global__ __launch_bounds__(256, 4) void attn_mfma_kernel(
    const __hip_bfloat16* __restrict__ Q,
    const __hip_bfloat16* __restrict__ K,
    const __hip_bfloat16* __restrict__ VT,
    __hip_bfloat16* __restrict__ O) {
    __shared__ __hip_bfloat16 ldsK[2][64][64];       // 16 KB
    __shared__ __hip_bfloat16 ldsVT[2][64][64];      // 16 KB
    __shared__ __hip_bfloat16 ldsP[4][16][64];       // 8 KB, XOR unit swizzle
    const int tx = threadIdx.x;
    const int wave = tx >> 6;
    const int lane = tx & 63;
    const int l16 = lane & 15;
    const int quad = lane >> 4;
    const int q0 = blockIdx.x * 64;
    const int h = blockIdx.y;
    const int kvh = h >> 1;
    const int b = blockIdx.z;
    const int qi = q0 + wave * 16 + l16;

    short8 aq[2];
    {
        const __hip_bfloat16* qp =
            Q + (size_t)(b * S_LEN + qi) * (NH * HD) + h * HD + quad * 8;
        aq[0] = *reinterpret_cast<const short8*>(qp);
        aq[1] = *reinterpret_cast<const short8*>(qp + 32);
    }
    f32x4 acc_o[4] = {};
    float m = -1e30f, l = 0.f;
    const float SL2 = 0.125f * 1.4426950408889634f;   // scale * log2(e)

    // staging: row = tx>>3 (+32), chunk-in-row = tx&7, XOR source swizzle
    const int s_row = tx >> 3;
    const int s_c8 = (((tx & 7) ^ (s_row & 7))) * 8;
    const int sw = (l16 & 7);                          // reader swizzle key
    auto stage = [&](int j0, int bf) {
        char* lk = (char*)(&ldsK[bf][0][0]) + tx * 16;
        char* lv = (char*)(&ldsVT[bf][0][0]) + tx * 16;
#pragma unroll
        for (int r = 0; r < 2; ++r) {
            int row = s_row + r * 32;
            GLOAD16(K + (size_t)(b * S_LEN + j0 + row) * (NKV * HD) + kvh * HD + s_c8,
                    lk + r * 4096);
            GLOAD16(VT + ((size_t)(b * NKV + kvh) * HD + row) * S_LEN + j0 + s_c8,
                    lv + r * 4096);
        }
    };

    const int kstart = (q0 >= WIN) ? (q0 - WIN) : 0;
    stage(kstart, 0);
    int buf = 0;

    char* prow = (char*)(&ldsP[wave][l16][0]);

    for (int j0 = kstart; j0 <= q0; j0 += 64) {
        __syncthreads();                              // drains DMA into [buf]
        if (j0 + 64 <= q0) stage(j0 + 64, buf ^ 1);   // async, lands by next barrier

        // S^T = K @ Q^T
        f32x4 sacc[4] = {};
#pragma unroll
        for (int t = 0; t < 4; ++t) {
            const __hip_bfloat16* krow = &ldsK[buf][t * 16 + l16][0];
            short8 bk0 = *reinterpret_cast<const short8*>(krow + ((quad ^ sw) * 8));
            short8 bk1 = *reinterpret_cast<const short8*>(krow + (((4 + quad) ^ sw) * 8));
            sacc[t] = __builtin_amdgcn_mfma_f32_16x16x32_bf16(bk0, aq[0], sacc[t], 0, 0, 0);
            sacc[t] = __builtin_amdgcn_mfma_f32_16x16x32_bf16(bk1, aq[1], sacc[t], 0, 0, 0);
        }

        const bool need_mask = (j0 == q0) || (q0 >= WIN && j0 == kstart);
        float sv[4][4];
        if (need_mask) {
#pragma unroll
            for (int t = 0; t < 4; ++t)
#pragma unroll
                for (int r = 0; r < 4; ++r) {
                    int j = j0 + t * 16 + quad * 4 + r;
                    bool ok = (j <= qi) && (j + WIN >= qi);
                    sv[t][r] = ok ? sacc[t][r] * SL2 : -1e30f;
                }
        } else {
#pragma unroll
            for (int t = 0; t < 4; ++t)
#pragma unroll
                for (int r = 0; r < 4; ++r) sv[t][r] = sacc[t][r] * SL2;
        }
        // online softmax (exp2 domain): in-lane reduce + 2 shuffles
        float cm = -1e30f;
#pragma unroll
        for (int t = 0; t < 4; ++t)
#pragma unroll
            for (int r = 0; r < 4; ++r) cm = fmaxf(cm, sv[t][r]);
        cm = fmaxf(cm, __shfl_xor(cm, 16));
        cm = fmaxf(cm, __shfl_xor(cm, 32));
        // T13 defer-max: skip rescale while the tile max stays within 8
        // (exp2 domain) of the running max; P then bounded by 2^8 = 256.
        if (!__all(cm - m <= 8.0f)) {
            float mn = fmaxf(m, cm);
            float alpha = exp2f(m - mn);
            m = mn;
            l *= alpha;
#pragma unroll
            for (int t = 0; t < 4; ++t)
#pragma unroll
                for (int r = 0; r < 4; ++r) acc_o[t][r] *= alpha;
        }
        float sp = 0.f;
#pragma unroll
        for (int t = 0; t < 4; ++t)
#pragma unroll
            for (int r = 0; r < 4; ++r) { sv[t][r] = exp2f(sv[t][r] - m); sp += sv[t][r]; }
        sp += __shfl_xor(sp, 16);
        sp += __shfl_xor(sp, 32);
        l += sp;
        // P^T -> LDS (XOR unit swizzle; wave-private, in-order)
#pragma unroll
        for (int t = 0; t < 4; ++t) {
            alignas(8) __hip_bfloat16 hp[4];
#pragma unroll
            for (int r = 0; r < 4; ++r) hp[r] = __float2bfloat16(sv[t][r]);
            int swb = ((((2 * t + (quad >> 1)) ^ (l16 & 7)) << 4) | ((quad & 1) << 3));
            *reinterpret_cast<ushort4*>(prow + swb) = *reinterpret_cast<ushort4*>(hp);
        }

        // O^T += VT @ P^T
#pragma unroll
        for (int ks = 0; ks < 2; ++ks) {
            short8 pf = *reinterpret_cast<const short8*>(
                prow + (((4 * ks + quad) ^ (l16 & 7)) << 4));
#pragma unroll
            for (int t = 0; t < 4; ++t) {
                const __hip_bfloat16* vrow = &ldsVT[buf][t * 16 + l16][0];
                short8 vf = *reinterpret_cast<const short8*>(
                    vrow + (((ks * 4 + quad) ^ sw) * 8));
                acc_o[t] = __builtin_amdgcn_mfma_f32_16x16x32_bf16(vf, pf, acc_o[t], 0, 0, 0);
            }
        }
        buf ^= 1;
    }

    {
        float inv = 1.f / l;
        __hip_bfloat16* op =
            O + (size_t)(b * S_LEN + qi) * (NH * HD) + h * HD;
#pragma unroll
        for (int t = 0; t < 4; ++t) {
            alignas(8) __hip_bfloat16 ho[4];
#pragma unroll
            for (int r = 0; r < 4; ++r) ho[r] = __float2bfloat16(acc_o[t][r] * inv);
            *reinterpret_cast<ushort4*>(op + t * 16 + quad * 4) =
                *reinterpret_cast<ushort4*>(ho);
        }
    }
}

// ---------------- launch ----------------
extern "C" void kernel_launch(void* const* d_in, const int* in_sizes, int n_in,
                              void* d_out, int out_size, void* d_ws, size_t ws_size,
                              hipStream_t stream) {
    const float* X  = (const float*)d_in[0];
    const float* Wq = (const float*)d_in[1];
    const float* Wk = (const float*)d_in[2];
    const float* Wv = (const float*)d_in[3];
    const float* Wo = (const float*)d_in[4];
    float* out = (float*)d_out;

    const int ROWS = 2 * S_LEN;               // 4096
    char* ws = (char*)d_ws;
    size_t off = 0;
    __hip_bfloat16* Xb     = (__hip_bfloat16*)(ws + off); off += (size_t)ROWS * DMODEL * 2;
    __hip_bfloat16* WqkvT  = (__hip_bfloat16*)(ws + off); off += (size_t)2048 * DMODEL * 2;
    __hip_bfloat16* WoT    = (__hip_bfloat16*)(ws + off); off += (size_t)DMODEL * DMODEL * 2;
    __hip_bfloat16* Qb     = (__hip_bfloat16*)(ws + off); off += (size_t)ROWS * (NH * HD) * 2;
    __hip_bfloat16* Kb     = (__hip_bfloat16*)(ws + off); off += (size_t)ROWS * (NKV * HD) * 2;
    __hip_bfloat16* VTg    = (__hip_bfloat16*)(ws + off); off += (size_t)ROWS * (NKV * HD) * 2;
    __hip_bfloat16* Ob     = (__hip_bfloat16*)(ws + off); off += (size_t)ROWS * (NH * HD) * 2;

    // 1. fused prep: X cast (z=4) + all weight transposes (z=0..3)
    prep_kernel<<<dim3(32, 32, 5), dim3(32, 8), 0, stream>>>(
        X, Wq, Wk, Wv, Wo, Xb, WqkvT, WoT);

    // 2. fused QKV projection + RoPE + V transpose (1024 blocks, BK=64)
    gemm128_kernel<0><<<dim3(2048 / 64, ROWS / 128), 256, 0, stream>>>(
        Xb, WqkvT, Qb, Kb, VTg, 2048, DMODEL);

    // 3. MFMA flash attention (head-split, 1024 blocks, 4/CU)
    attn_mfma_kernel<<<dim3(S_LEN / 64, NH, 2), 256, 0, stream>>>(Qb, Kb, VTg, Ob);

    // 4. output projection -> fp32 (512 blocks, BK=64)
    gemm128_kernel<1><<<dim3(DMODEL / 64, ROWS / 128), 256, 0, stream>>>(
        Ob, WoT, out, nullptr, nullptr, DMODEL, DMODEL);
}

// Round 4
// 147.481 us; speedup vs baseline: 1.1285x; 1.0476x over previous
//
#include <hip/hip_runtime.h>
#include <hip/hip_bf16.h>

typedef __attribute__((ext_vector_type(8))) short short8;
typedef __attribute__((ext_vector_type(4))) float f32x4;

#define S_LEN 2048
#define NH 16
#define NKV 8
#define HD 64
#define WIN 512
#define DMODEL 1024
#define LOG2_10000 13.287712379549449f

// async 16B global -> LDS (wave-uniform LDS base + lane*16 semantics)
#define GLOAD16(g, l)                                                        \
    __builtin_amdgcn_global_load_lds(                                        \
        (const __attribute__((address_space(1))) unsigned int*)(g),          \
        (__attribute__((address_space(3))) unsigned int*)(l), 16, 0, 0)

// ------- prep: fused X-cast (z=4) + transpose+cast of 4 weights (z=0..3) ----
__global__ void prep_kernel(const float* __restrict__ X,
                            const float* __restrict__ W0,
                            const float* __restrict__ W1,
                            const float* __restrict__ W2,
                            const float* __restrict__ W3,
                            __hip_bfloat16* __restrict__ Xb,
                            __hip_bfloat16* __restrict__ WqkvT,
                            __hip_bfloat16* __restrict__ WoT) {
    if (blockIdx.z == 4) {                         // X cast: fp32 -> bf16
        int tid = (blockIdx.y * 32 + blockIdx.x) * 256 + threadIdx.y * 32 + threadIdx.x;
        const float4* Xi = reinterpret_cast<const float4*>(X);
#pragma unroll
        for (int r = 0; r < 4; ++r) {
            int i = tid + r * (1024 * 256);        // float4 index
            float4 v = Xi[i];
            alignas(8) __hip_bfloat16 h[4];
            h[0] = __float2bfloat16(v.x);
            h[1] = __float2bfloat16(v.y);
            h[2] = __float2bfloat16(v.z);
            h[3] = __float2bfloat16(v.w);
            *reinterpret_cast<ushort4*>(Xb + (size_t)i * 4) =
                *reinterpret_cast<ushort4*>(h);
        }
        return;
    }
    __shared__ float tile[32][33];
    const int K = DMODEL;
    const float* W;
    __hip_bfloat16* WT;
    int N;
    switch (blockIdx.z) {
        case 0: W = W0; WT = WqkvT;                          N = 1024; break;
        case 1: W = W1; WT = WqkvT + (size_t)1024 * K;       N = 512;  break;
        case 2: W = W2; WT = WqkvT + (size_t)1536 * K;       N = 512;  break;
        default: W = W3; WT = WoT;                           N = 1024; break;
    }
    if ((int)blockIdx.x * 32 >= N) return;
    int nx = blockIdx.x * 32 + threadIdx.x;
    int k0 = blockIdx.y * 32;
#pragma unroll
    for (int r = 0; r < 4; ++r) {
        int k = k0 + threadIdx.y + r * 8;
        tile[threadIdx.y + r * 8][threadIdx.x] = W[(size_t)k * N + nx];
    }
    __syncthreads();
#pragma unroll
    for (int r = 0; r < 4; ++r) {
        int nn = blockIdx.x * 32 + threadIdx.y + r * 8;
        int kk = k0 + threadIdx.x;
        WT[(size_t)nn * K + kk] = __float2bfloat16(tile[threadIdx.x][threadIdx.y + r * 8]);
    }
}

// ---------- QKV GEMM: 128x128 tile, 4 waves (2x2 of 64x64), BK=64 ----------
// ROUND 17: r16's 128x64 tile had 12 ds_read_b128 (~144 cyc issue) vs 16 MFMA
// (~78 cyc) per wave-iteration — LDS-issue-bound (m80 failure mode; m102's
// ~320 TF regime). 64x64 wave-tile: 16 ds_read vs 32 MFMA — MFMA-dominant.
// Grid 512 = 2 blocks/CU exactly; LDS 64 KB fits 2/CU (grid only supplies
// 2/CU, so no occupancy loss a la m132). Both-sides XOR involution on the
// 128 B LDS rows (rule #21; same verified pattern as attn staging).
// In-register RoPE on Q/K (__cosf/__sinf ONLY — libm spills the acc array).
__global__ __launch_bounds__(256, 2) void gemm_qkv_kernel(
    const __hip_bfloat16* __restrict__ A,
    const __hip_bfloat16* __restrict__ BT,
    __hip_bfloat16* __restrict__ Qo,
    __hip_bfloat16* __restrict__ Ko,
    __hip_bfloat16* __restrict__ VTo) {
    const int K = DMODEL;
    __shared__ __hip_bfloat16 ldsA[2][128 * 64];   // 32 KB
    __shared__ __hip_bfloat16 ldsB[2][128 * 64];   // 32 KB
    const int tx = threadIdx.x;
    const int wave = tx >> 6;
    const int lane = tx & 63;
    const int l16 = lane & 15;
    const int quad = lane >> 4;
    const int col0 = blockIdx.x * 128;
    const int row0 = blockIdx.y * 128;
    const int wrow = (wave >> 1) * 64;
    const int wcol = (wave & 1) * 64;
    const int sw = l16 & 7;                        // reader swizzle key

    f32x4 acc[4][4] = {};

    // staging: row = tx>>3 (0..31), chunk = tx&7, XOR source swizzle
    const int arow = tx >> 3;
    const int cs8 = ((tx & 7) ^ (arow & 7)) * 8;   // swizzled source chunk
    const __hip_bfloat16* gA = A + (size_t)(row0 + arow) * K + cs8;
    const __hip_bfloat16* gB = BT + (size_t)(col0 + arow) * K + cs8;

    auto stage = [&](int k0, int bf) {
        char* lA = (char*)(&ldsA[bf][0]) + tx * 16;
        char* lB = (char*)(&ldsB[bf][0]) + tx * 16;
#pragma unroll
        for (int r = 0; r < 4; ++r) {              // rows r*32 .. r*32+31
            GLOAD16(gA + (size_t)(r * 32) * K + k0, lA + r * 4096);
            GLOAD16(gB + (size_t)(r * 32) * K + k0, lB + r * 4096);
        }
    };

    stage(0, 0);
    int buf = 0;
    for (int k0 = 0; k0 < K; k0 += 64) {
        __syncthreads();                            // drains DMA into [buf]
        if (k0 + 64 < K) stage(k0 + 64, buf ^ 1);   // lands by next barrier
        short8 af[4][2], bf4[4][2];
#pragma unroll
        for (int i = 0; i < 4; ++i) {
            const char* ar = (const char*)(&ldsA[buf][0]) + (wrow + i * 16 + l16) * 128;
            const char* br = (const char*)(&ldsB[buf][0]) + (wcol + i * 16 + l16) * 128;
#pragma unroll
            for (int ks = 0; ks < 2; ++ks) {
                af[i][ks] = *reinterpret_cast<const short8*>(
                    ar + (((ks * 4 + quad) ^ sw) << 4));
                bf4[i][ks] = *reinterpret_cast<const short8*>(
                    br + (((ks * 4 + quad) ^ sw) << 4));
            }
        }
#pragma unroll
        for (int ks = 0; ks < 2; ++ks)
#pragma unroll
            for (int mi = 0; mi < 4; ++mi)
#pragma unroll
                for (int ni = 0; ni < 4; ++ni)
                    acc[mi][ni] = __builtin_amdgcn_mfma_f32_16x16x32_bf16(
                        af[mi][ks], bf4[ni][ks], acc[mi][ni], 0, 0, 0);
        buf ^= 1;
    }

    const int rbase = row0 + wrow;
    const int cbaseg = col0 + wcol;                 // 64-aligned global col
    const bool isQ = (cbaseg < DMODEL);
    const bool isK = (cbaseg >= DMODEL) && (cbaseg < DMODEL + 512);
    if (isQ || isK) {
        float invf[2];
        invf[0] = exp2f(-(float)(l16)      * (LOG2_10000 / 32.0f));
        invf[1] = exp2f(-(float)(16 + l16) * (LOG2_10000 / 32.0f));
#pragma unroll
        for (int mi = 0; mi < 4; ++mi)
#pragma unroll
            for (int r = 0; r < 4; ++r) {
                int srow = (rbase + mi * 16 + quad * 4 + r) & (S_LEN - 1);
#pragma unroll
                for (int ni = 0; ni < 2; ++ni) {
                    float ang = (float)srow * invf[ni];
                    float c = __cosf(ang), s = __sinf(ang);
                    float x1 = acc[mi][ni][r], x2 = acc[mi][ni + 2][r];
                    acc[mi][ni][r]     = x1 * c - x2 * s;
                    acc[mi][ni + 2][r] = x2 * c + x1 * s;
                }
            }
        __hip_bfloat16* Co = isQ ? Qo : Ko;
        int cbase = isQ ? cbaseg : cbaseg - DMODEL;
        int rowstride = isQ ? (NH * HD) : (NKV * HD);
#pragma unroll
        for (int mi = 0; mi < 4; ++mi)
#pragma unroll
            for (int ni = 0; ni < 4; ++ni) {
                size_t col = cbase + ni * 16 + l16;
#pragma unroll
                for (int r = 0; r < 4; ++r)
                    Co[(size_t)(rbase + mi * 16 + quad * 4 + r) * rowstride + col] =
                        __float2bfloat16(acc[mi][ni][r]);
            }
    } else {                                       // V region -> transposed VT
        int bb = row0 >> 11;
#pragma unroll
        for (int mi = 0; mi < 4; ++mi) {
            int s = ((rbase + mi * 16 + quad * 4) & (S_LEN - 1));
#pragma unroll
            for (int ni = 0; ni < 4; ++ni) {
                int colv = cbaseg - 1536 + ni * 16 + l16;   // 0..511
                int vh = colv >> 6, d = colv & 63;
                alignas(8) __hip_bfloat16 hv[4];
#pragma unroll
                for (int r = 0; r < 4; ++r) hv[r] = __float2bfloat16(acc[mi][ni][r]);
                *reinterpret_cast<ushort4*>(
                    VTo + ((size_t)(bb * NKV + vh) * HD + d) * S_LEN + s) =
                    *reinterpret_cast<ushort4*>(hv);
            }
        }
    }
}

// ------------- out-proj GEMM: 128(M)x64(N) tile, 4 waves, BK=64 -------------
// (r16 structure, frozen this round; fp32 C output)
__global__ __launch_bounds__(256, 4) void gemm128_kernel(
    const __hip_bfloat16* __restrict__ A,
    const __hip_bfloat16* __restrict__ BT,
    float* __restrict__ Co, int N, int K) {
    __shared__ __hip_bfloat16 ldsA[2][128 * 64];   // 32 KB
    __shared__ __hip_bfloat16 ldsB[2][64 * 64];    // 16 KB
    const int tx = threadIdx.x;
    const int wave = tx >> 6;
    const int lane = tx & 63;
    const int l16 = lane & 15;
    const int quad = lane >> 4;
    const int col0 = blockIdx.x * 64;
    const int row0 = blockIdx.y * 128;
    const int wrow = wave * 32;
    const int sw = l16 & 7;                        // reader swizzle key

    f32x4 acc[2][4] = {};

    // staging: row = tx>>3 (0..31), chunk = tx&7, XOR source swizzle
    const int arow = tx >> 3;
    const int cs8 = ((tx & 7) ^ (arow & 7)) * 8;   // swizzled source chunk
    const __hip_bfloat16* gA = A + (size_t)(row0 + arow) * K + cs8;
    const __hip_bfloat16* gB = BT + (size_t)(col0 + arow) * K + cs8;

    auto stage = [&](int k0, int bf) {
        char* lA = (char*)(&ldsA[bf][0]) + tx * 16;
        char* lB = (char*)(&ldsB[bf][0]) + tx * 16;
#pragma unroll
        for (int r = 0; r < 4; ++r)                // A rows r*32 .. r*32+31
            GLOAD16(gA + (size_t)(r * 32) * K + k0, lA + r * 4096);
#pragma unroll
        for (int r = 0; r < 2; ++r)                // B rows r*32 .. r*32+31
            GLOAD16(gB + (size_t)(r * 32) * K + k0, lB + r * 4096);
    };

    stage(0, 0);
    int buf = 0;
    for (int k0 = 0; k0 < K; k0 += 64) {
        __syncthreads();                            // drains DMA into [buf]
        if (k0 + 64 < K) stage(k0 + 64, buf ^ 1);   // lands by next barrier
        short8 af[2][2], bf4[4][2];
#pragma unroll
        for (int i = 0; i < 2; ++i) {
            const char* ar = (const char*)(&ldsA[buf][0]) + (wrow + i * 16 + l16) * 128;
#pragma unroll
            for (int ks = 0; ks < 2; ++ks)
                af[i][ks] = *reinterpret_cast<const short8*>(
                    ar + (((ks * 4 + quad) ^ sw) << 4));
        }
#pragma unroll
        for (int i = 0; i < 4; ++i) {
            const char* br = (const char*)(&ldsB[buf][0]) + (i * 16 + l16) * 128;
#pragma unroll
            for (int ks = 0; ks < 2; ++ks)
                bf4[i][ks] = *reinterpret_cast<const short8*>(
                    br + (((ks * 4 + quad) ^ sw) << 4));
        }
#pragma unroll
        for (int ks = 0; ks < 2; ++ks)
#pragma unroll
            for (int mi = 0; mi < 2; ++mi)
#pragma unroll
                for (int ni = 0; ni < 4; ++ni)
                    acc[mi][ni] = __builtin_amdgcn_mfma_f32_16x16x32_bf16(
                        af[mi][ks], bf4[ni][ks], acc[mi][ni], 0, 0, 0);
        buf ^= 1;
    }

    const int rbase = row0 + wrow;
#pragma unroll
    for (int mi = 0; mi < 2; ++mi)
#pragma unroll
        for (int ni = 0; ni < 4; ++ni) {
            size_t col = col0 + ni * 16 + l16;
#pragma unroll
            for (int r = 0; r < 4; ++r)
                Co[(size_t)(rbase + mi * 16 + quad * 4 + r) * N + col] = acc[mi][ni][r];
        }
}

// ---------------- MFMA flash attention: head-split, DMA dbuf, swizzled ----
// ROUND 14: head-split, grid (32,16,2)=1024, 40 KB LDS -> 4 blocks/CU.
// ROUND 15: + T13 defer-max (skip alpha-rescale when per-tile max growth
// <= 8 in exp2 domain; P bounded by 256, fine in bf16/f32 — m214v23/m239).
__global__ __launch_bounds__(256, 4) void attn_mfma_kernel(
    const __hip_bfloat16* __restrict__ Q,
    const __hip_bfloat16* __restrict__ K,
    const __hip_bfloat16* __restrict__ VT,
    __hip_bfloat16* __restrict__ O) {
    __shared__ __hip_bfloat16 ldsK[2][64][64];       // 16 KB
    __shared__ __hip_bfloat16 ldsVT[2][64][64];      // 16 KB
    __shared__ __hip_bfloat16 ldsP[4][16][64];       // 8 KB, XOR unit swizzle
    const int tx = threadIdx.x;
    const int wave = tx >> 6;
    const int lane = tx & 63;
    const int l16 = lane & 15;
    const int quad = lane >> 4;
    const int q0 = blockIdx.x * 64;
    const int h = blockIdx.y;
    const int kvh = h >> 1;
    const int b = blockIdx.z;
    const int qi = q0 + wave * 16 + l16;

    short8 aq[2];
    {
        const __hip_bfloat16* qp =
            Q + (size_t)(b * S_LEN + qi) * (NH * HD) + h * HD + quad * 8;
        aq[0] = *reinterpret_cast<const short8*>(qp);
        aq[1] = *reinterpret_cast<const short8*>(qp + 32);
    }
    f32x4 acc_o[4] = {};
    float m = -1e30f, l = 0.f;
    const float SL2 = 0.125f * 1.4426950408889634f;   // scale * log2(e)

    // staging: row = tx>>3 (+32), chunk-in-row = tx&7, XOR source swizzle
    const int s_row = tx >> 3;
    const int s_c8 = (((tx & 7) ^ (s_row & 7))) * 8;
    const int sw = (l16 & 7);                          // reader swizzle key
    auto stage = [&](int j0, int bf) {
        char* lk = (char*)(&ldsK[bf][0][0]) + tx * 16;
        char* lv = (char*)(&ldsVT[bf][0][0]) + tx * 16;
#pragma unroll
        for (int r = 0; r < 2; ++r) {
            int row = s_row + r * 32;
            GLOAD16(K + (size_t)(b * S_LEN + j0 + row) * (NKV * HD) + kvh * HD + s_c8,
                    lk + r * 4096);
            GLOAD16(VT + ((size_t)(b * NKV + kvh) * HD + row) * S_LEN + j0 + s_c8,
                    lv + r * 4096);
        }
    };

    const int kstart = (q0 >= WIN) ? (q0 - WIN) : 0;
    stage(kstart, 0);
    int buf = 0;

    char* prow = (char*)(&ldsP[wave][l16][0]);

    for (int j0 = kstart; j0 <= q0; j0 += 64) {
        __syncthreads();                              // drains DMA into [buf]
        if (j0 + 64 <= q0) stage(j0 + 64, buf ^ 1);   // async, lands by next barrier

        // S^T = K @ Q^T
        f32x4 sacc[4] = {};
#pragma unroll
        for (int t = 0; t < 4; ++t) {
            const __hip_bfloat16* krow = &ldsK[buf][t * 16 + l16][0];
            short8 bk0 = *reinterpret_cast<const short8*>(krow + ((quad ^ sw) * 8));
            short8 bk1 = *reinterpret_cast<const short8*>(krow + (((4 + quad) ^ sw) * 8));
            sacc[t] = __builtin_amdgcn_mfma_f32_16x16x32_bf16(bk0, aq[0], sacc[t], 0, 0, 0);
            sacc[t] = __builtin_amdgcn_mfma_f32_16x16x32_bf16(bk1, aq[1], sacc[t], 0, 0, 0);
        }

        const bool need_mask = (j0 == q0) || (q0 >= WIN && j0 == kstart);
        float sv[4][4];
        if (need_mask) {
#pragma unroll
            for (int t = 0; t < 4; ++t)
#pragma unroll
                for (int r = 0; r < 4; ++r) {
                    int j = j0 + t * 16 + quad * 4 + r;
                    bool ok = (j <= qi) && (j + WIN >= qi);
                    sv[t][r] = ok ? sacc[t][r] * SL2 : -1e30f;
                }
        } else {
#pragma unroll
            for (int t = 0; t < 4; ++t)
#pragma unroll
                for (int r = 0; r < 4; ++r) sv[t][r] = sacc[t][r] * SL2;
        }
        // online softmax (exp2 domain): in-lane reduce + 2 shuffles
        float cm = -1e30f;
#pragma unroll
        for (int t = 0; t < 4; ++t)
#pragma unroll
            for (int r = 0; r < 4; ++r) cm = fmaxf(cm, sv[t][r]);
        cm = fmaxf(cm, __shfl_xor(cm, 16));
        cm = fmaxf(cm, __shfl_xor(cm, 32));
        // T13 defer-max: skip rescale while the tile max stays within 8
        // (exp2 domain) of the running max; P then bounded by 2^8 = 256.
        if (!__all(cm - m <= 8.0f)) {
            float mn = fmaxf(m, cm);
            float alpha = exp2f(m - mn);
            m = mn;
            l *= alpha;
#pragma unroll
            for (int t = 0; t < 4; ++t)
#pragma unroll
                for (int r = 0; r < 4; ++r) acc_o[t][r] *= alpha;
        }
        float sp = 0.f;
#pragma unroll
        for (int t = 0; t < 4; ++t)
#pragma unroll
            for (int r = 0; r < 4; ++r) { sv[t][r] = exp2f(sv[t][r] - m); sp += sv[t][r]; }
        sp += __shfl_xor(sp, 16);
        sp += __shfl_xor(sp, 32);
        l += sp;
        // P^T -> LDS (XOR unit swizzle; wave-private, in-order)
#pragma unroll
        for (int t = 0; t < 4; ++t) {
            alignas(8) __hip_bfloat16 hp[4];
#pragma unroll
            for (int r = 0; r < 4; ++r) hp[r] = __float2bfloat16(sv[t][r]);
            int swb = ((((2 * t + (quad >> 1)) ^ (l16 & 7)) << 4) | ((quad & 1) << 3));
            *reinterpret_cast<ushort4*>(prow + swb) = *reinterpret_cast<ushort4*>(hp);
        }

        // O^T += VT @ P^T
#pragma unroll
        for (int ks = 0; ks < 2; ++ks) {
            short8 pf = *reinterpret_cast<const short8*>(
                prow + (((4 * ks + quad) ^ (l16 & 7)) << 4));
#pragma unroll
            for (int t = 0; t < 4; ++t) {
                const __hip_bfloat16* vrow = &ldsVT[buf][t * 16 + l16][0];
                short8 vf = *reinterpret_cast<const short8*>(
                    vrow + (((ks * 4 + quad) ^ sw) * 8));
                acc_o[t] = __builtin_amdgcn_mfma_f32_16x16x32_bf16(vf, pf, acc_o[t], 0, 0, 0);
            }
        }
        buf ^= 1;
    }

    {
        float inv = 1.f / l;
        __hip_bfloat16* op =
            O + (size_t)(b * S_LEN + qi) * (NH * HD) + h * HD;
#pragma unroll
        for (int t = 0; t < 4; ++t) {
            alignas(8) __hip_bfloat16 ho[4];
#pragma unroll
            for (int r = 0; r < 4; ++r) ho[r] = __float2bfloat16(acc_o[t][r] * inv);
            *reinterpret_cast<ushort4*>(op + t * 16 + quad * 4) =
                *reinterpret_cast<ushort4*>(ho);
        }
    }
}

// ---------------- launch ----------------
extern "C" void kernel_launch(void* const* d_in, const int* in_sizes, int n_in,
                              void* d_out, int out_size, void* d_ws, size_t ws_size,
                              hipStream_t stream) {
    const float* X  = (const float*)d_in[0];
    const float* Wq = (const float*)d_in[1];
    const float* Wk = (const float*)d_in[2];
    const float* Wv = (const float*)d_in[3];
    const float* Wo = (const float*)d_in[4];
    float* out = (float*)d_out;

    const int ROWS = 2 * S_LEN;               // 4096
    char* ws = (char*)d_ws;
    size_t off = 0;
    __hip_bfloat16* Xb     = (__hip_bfloat16*)(ws + off); off += (size_t)ROWS * DMODEL * 2;
    __hip_bfloat16* WqkvT  = (__hip_bfloat16*)(ws + off); off += (size_t)2048 * DMODEL * 2;
    __hip_bfloat16* WoT    = (__hip_bfloat16*)(ws + off); off += (size_t)DMODEL * DMODEL * 2;
    __hip_bfloat16* Qb     = (__hip_bfloat16*)(ws + off); off += (size_t)ROWS * (NH * HD) * 2;
    __hip_bfloat16* Kb     = (__hip_bfloat16*)(ws + off); off += (size_t)ROWS * (NKV * HD) * 2;
    __hip_bfloat16* VTg    = (__hip_bfloat16*)(ws + off); off += (size_t)ROWS * (NKV * HD) * 2;
    __hip_bfloat16* Ob     = (__hip_bfloat16*)(ws + off); off += (size_t)ROWS * (NH * HD) * 2;

    // 1. fused prep: X cast (z=4) + all weight transposes (z=0..3)
    prep_kernel<<<dim3(32, 32, 5), dim3(32, 8), 0, stream>>>(
        X, Wq, Wk, Wv, Wo, Xb, WqkvT, WoT);

    // 2. fused QKV projection + RoPE + V transpose (128x128 tile, 512 blocks)
    gemm_qkv_kernel<<<dim3(2048 / 128, ROWS / 128), 256, 0, stream>>>(
        Xb, WqkvT, Qb, Kb, VTg);

    // 3. MFMA flash attention (head-split, 1024 blocks, 4/CU)
    attn_mfma_kernel<<<dim3(S_LEN / 64, NH, 2), 256, 0, stream>>>(Qb, Kb, VTg, Ob);

    // 4. output projection -> fp32 (512 blocks, BK=64)
    gemm128_kernel<<<dim3(DMODEL / 64, ROWS / 128), 256, 0, stream>>>(
        Ob, WoT, out, DMODEL, DMODEL);
}